// Round 3
// baseline (426.421 us; speedup 1.0000x reference)
//
#include <hip/hip_runtime.h>
#include <stdint.h>

#define D 128
#define BB 512
#define NLEVELS 8

typedef __bf16 bf16x8 __attribute__((ext_vector_type(8)));
typedef float f32x4  __attribute__((ext_vector_type(4)));

__device__ __forceinline__ float b2f(ushort u) {
    uint x = ((uint)u) << 16;
    return __builtin_bit_cast(float, x);
}
__device__ __forceinline__ ushort f2b(float f) {   // round-to-nearest-even
    uint u = __builtin_bit_cast(uint, f);
    u += 0x7FFFu + ((u >> 16) & 1u);
    return (ushort)(u >> 16);
}
// swizzle: XOR low-3 bits of the 16B slot with the 512B pair-row index
__device__ __forceinline__ int swz(int b) { return b ^ (((b >> 9) & 7) << 4); }

// ---------------------------------------------------------------------------
// Weight packing (fragment-major bf16): W1p[((kk*16+nt)*64+lane)*8+t] =
//   W1[kk*32 + 8*(lane>>4) + t][nt*16 + (lane&15)]  (B-operand layout, 16x16x32)
// ---------------------------------------------------------------------------
__global__ void pack_w_kernel(const float* __restrict__ W1, const float* __restrict__ W2,
                              ushort* __restrict__ W1p, ushort* __restrict__ W2p) {
    int g = blockIdx.x * blockDim.x + threadIdx.x;
    if (g < 65536) {
        int t = g & 7, l = (g >> 3) & 63, nt = (g >> 9) & 15, kk = g >> 13;
        int krow = kk * 32 + (l >> 4) * 8 + t;
        int col  = nt * 16 + (l & 15);
        W1p[g] = f2b(W1[krow * 256 + col]);
    } else {
        int g2 = g - 65536;
        if (g2 < 32768) {
            int t = g2 & 7, l = (g2 >> 3) & 63, nt = (g2 >> 9) & 7, kk = g2 >> 12;
            int krow = kk * 32 + (l >> 4) * 8 + t;
            int col  = nt * 16 + (l & 15);
            W2p[g2] = f2b(W2[krow * 128 + col]);
        }
    }
}

// ---------------------------------------------------------------------------
// Block-wide inclusive scan (512 threads), u64 payload (multi-digit counters).
// ---------------------------------------------------------------------------
__device__ __forceinline__ unsigned long long block_scan_u64(unsigned long long v,
                                                             unsigned long long* wsum) {
    int lane = threadIdx.x & 63, wv = threadIdx.x >> 6;
    unsigned long long x = v;
    #pragma unroll
    for (int o = 1; o < 64; o <<= 1) {
        unsigned long long y = __shfl_up(x, (unsigned)o, 64);
        if (lane >= o) x += y;
    }
    if (lane == 63) wsum[wv] = x;
    __syncthreads();
    if (threadIdx.x == 0) {
        unsigned long long acc = 0;
        for (int i = 0; i < 8; ++i) { unsigned long long t = wsum[i]; wsum[i] = acc; acc += t; }
    }
    __syncthreads();
    unsigned long long r = x + wsum[wv];
    __syncthreads();
    return r;
}

// ---------------------------------------------------------------------------
// Plan: pow2-pad each item (min 4 rows), counting-sort by size descending
// (pow2 sizes never straddle a 256-row bin boundary), emit per-bin tables.
// NOTE: limits is int32 (harness converts integer inputs to int*).
// ---------------------------------------------------------------------------
__global__ void __launch_bounds__(512) plan_kernel(
    const int* __restrict__ limits,
    ushort* __restrict__ sortedIdx, ushort* __restrict__ offRows,
    ushort* __restrict__ binStart, int* __restrict__ nbinsOut)
{
    __shared__ unsigned long long wsum[8];
    __shared__ int cnt[16], base[16];
    __shared__ ushort p2a[512], sIdx[512], binA[512];
    const int tid = threadIdx.x;

    int Lm = limits[tid + 1] - limits[tid];
    Lm = min(max(Lm, 1), 256);            // defensive clamp
    int p2 = (Lm <= 1) ? 4 : (1 << (32 - __clz(Lm - 1)));
    if (p2 < 4) p2 = 4;
    int cls = 31 - __clz(p2);             // 2..8
    p2a[tid] = (ushort)p2;
    if (tid < 16) cnt[tid] = 0;
    __syncthreads();
    atomicAdd(&cnt[cls], 1);              // order-independent counts
    __syncthreads();
    if (tid == 0) {
        int b = 0;
        for (int c = 8; c >= 2; --c) { base[c] = b; b += cnt[c]; }
    }
    __syncthreads();

    // rank within class via multi-digit scans (16-bit digits, max 512 fits)
    unsigned long long va = (cls <= 5) ? (1ull << ((cls - 2) * 16)) : 0ull;
    unsigned long long vb = (cls >= 6) ? (1ull << ((cls - 6) * 16)) : 0ull;
    unsigned long long ia = block_scan_u64(va, wsum);
    unsigned long long ib = block_scan_u64(vb, wsum);
    int rank = (cls <= 5) ? (int)((ia >> ((cls - 2) * 16)) & 0xFFFF) - 1
                          : (int)((ib >> ((cls - 6) * 16)) & 0xFFFF) - 1;
    int pos = base[cls] + rank;
    sIdx[pos] = (ushort)tid;
    __syncthreads();

    // padded cumsum in sorted order
    unsigned long long pv = (unsigned long long)p2a[sIdx[tid]];
    unsigned long long ic = block_scan_u64(pv, wsum);
    unsigned int cumB = (unsigned int)(ic - pv);
    int bin = (int)(cumB >> 8);
    binA[tid] = (ushort)bin;
    sortedIdx[tid] = sIdx[tid];
    offRows[tid]  = (ushort)(cumB & 255);
    __syncthreads();
    if (tid == 0) binStart[0] = 0;
    else if (binA[tid] != binA[tid - 1]) binStart[bin] = (ushort)tid;
    if (tid == 511) { nbinsOut[0] = bin + 1; binStart[bin + 1] = 512; }
}

// ---------------------------------------------------------------------------
// Fused tree kernel: one block = one bin (<=64 items, <=256 live rows in LDS).
// Per level: build pair schedule -> GEMM1(256x256)+ReLU(H in-place) ->
// GEMM2(256x128)+LayerNorm -> compact outputs, all in one 64KB LDS buffer.
// ---------------------------------------------------------------------------
__global__ void __launch_bounds__(256, 2) tree_kernel(
    const float* __restrict__ args, const int* __restrict__ limits,
    const ushort* __restrict__ W1p, const ushort* __restrict__ W2p,
    const float* __restrict__ b1, const float* __restrict__ b2,
    const float* __restrict__ lnw, const float* __restrict__ lnb,
    const ushort* __restrict__ sortedIdx, const ushort* __restrict__ offRows,
    const ushort* __restrict__ binStart, const int* __restrict__ nbinsP,
    float* __restrict__ out)
{
    if ((int)blockIdx.x >= *nbinsP) return;

    __shared__ __align__(16) char Xw[65536];
    __shared__ unsigned int sched[128];
    __shared__ ushort itOff[64], itL[64], itCur[64], itOut[64], itYb[64], cpS[64];
    __shared__ ushort startP[65];
    __shared__ int itRow[64];
    __shared__ int rowsrc[256];
    __shared__ int gmisc[4];   // 0:G  1:nlev  2:nP

    const int tid = threadIdx.x, lane = tid & 63, w = tid >> 6;

    if (tid == 0) gmisc[0] = (int)binStart[blockIdx.x + 1] - (int)binStart[blockIdx.x];
    __syncthreads();
    const int G = gmisc[0];

    if (tid < G) {
        int pos = (int)binStart[blockIdx.x] + tid;
        int it = sortedIdx[pos];
        itOff[tid] = offRows[pos];
        int a0 = limits[it];
        int Lm = limits[it + 1] - a0;
        Lm = min(max(Lm, 1), 256);
        itL[tid] = (ushort)Lm; itCur[tid] = (ushort)Lm;
        itRow[tid] = a0;  itOut[tid] = (ushort)it;
    }
    if (tid < 64) {
        int lev = 0;
        if (tid < G) { int Lm = (int)itL[tid]; lev = (Lm > 1) ? (32 - __clz(Lm - 1)) : 0; }
        #pragma unroll
        for (int o = 32; o; o >>= 1) lev = max(lev, __shfl_xor(lev, o, 64));
        if (tid == 0) gmisc[1] = lev;
    }
    __syncthreads();
    const int nlev = gmisc[1];

    // per-lane constant epilogue params
    float bb1[4], bb2[8], lw[8], lb[8];
    #pragma unroll
    for (int n = 0; n < 4; ++n) bb1[n] = b1[(w * 4 + n) * 16 + (lane & 15)];
    #pragma unroll
    for (int nt = 0; nt < 8; ++nt) {
        int c = nt * 16 + (lane & 15);
        bb2[nt] = b2[c]; lw[nt] = lnw[c]; lb[nt] = lnb[c];
    }

    // ---- rowsrc map + leaf staging (f32 -> bf16, swizzled ds_write) ----
    {
        int r = tid;
        int lo = 0, hi = G;
        while (hi - lo > 1) { int mid = (lo + hi) >> 1; if ((int)itOff[mid] <= r) lo = mid; else hi = mid; }
        int rel = r - (int)itOff[lo];
        rowsrc[r] = (rel >= 0 && rel < (int)itL[lo]) ? (itRow[lo] + rel) : -1;
    }
    __syncthreads();
    #pragma unroll
    for (int q = 0; q < 16; ++q) {
        int job = tid + q * 256;
        int r = job >> 4, ch = job & 15;
        int src = rowsrc[r];
        if (src >= 0) {
            const float4 f0 = *(const float4*)(args + (size_t)src * D + ch * 8);
            const float4 f1 = *(const float4*)(args + (size_t)src * D + ch * 8 + 4);
            uint4 pk;
            pk.x = (uint)f2b(f0.x) | ((uint)f2b(f0.y) << 16);
            pk.y = (uint)f2b(f0.z) | ((uint)f2b(f0.w) << 16);
            pk.z = (uint)f2b(f1.x) | ((uint)f2b(f1.y) << 16);
            pk.w = (uint)f2b(f1.z) | ((uint)f2b(f1.w) << 16);
            *(uint4*)(Xw + swz(r * 256 + ch * 16)) = pk;
        }
    }
    __syncthreads();

    // ---- level loop ----
    for (int k = 0; k < nlev; ++k) {
        // (a) schedule generation (wave 0 does item math)
        if (tid < 64) {
            int l = (tid < G) ? (int)itCur[tid] : 0;
            int p = l >> 1;
            int x = p;
            #pragma unroll
            for (int o = 1; o < 64; o <<= 1) { int y = __shfl_up(x, (unsigned)o, 64); if (lane >= o) x += y; }
            int excl = x - p;
            if (tid < G) {
                startP[tid] = (ushort)excl;
                itYb[tid]   = (ushort)((int)itOff[tid] + (l & 1));
                cpS[tid]    = (l > 1 && (l & 1)) ? (ushort)((int)itOff[tid] + l - 1) : (ushort)0xFFFF;
                itCur[tid]  = (ushort)(p + (l & 1));
            }
            if (tid == 63) gmisc[2] = x;
        }
        __syncthreads();
        const int nP = gmisc[2];
        if (nP == 0) break;
        const int nMf = (nP + 15) >> 4;
        const int nPpad = nMf << 4;
        if (tid < nPpad) {
            unsigned int entry;
            if (tid < nP) {
                int lo = 0, hi = G;
                while (hi - lo > 1) { int mid = (lo + hi) >> 1; if ((int)startP[mid] <= tid) lo = mid; else hi = mid; }
                int j = tid - (int)startP[lo];
                entry = (unsigned)(((int)itOff[lo] >> 1) + j) | ((unsigned)((int)itYb[lo] + j) << 16);
            } else {
                entry = 0u | (0xFFFFu << 16);
            }
            sched[tid] = entry;
        }
        __syncthreads();

        // per-lane schedule fragments (prow for pairIdx = mf*16 + (lane&15))
        unsigned int pa[8];
        #pragma unroll
        for (int mf = 0; mf < 8; ++mf)
            pa[mf] = (mf < nMf) ? sched[mf * 16 + (lane & 15)] : (0xFFFFu << 16);

        // (b) GEMM1: H = relu(X @ W1 + b1), N split across waves (4 nt each)
        f32x4 acc1[8][4];
        #pragma unroll
        for (int mf = 0; mf < 8; ++mf)
            #pragma unroll
            for (int n = 0; n < 4; ++n) acc1[mf][n] = f32x4{0.f, 0.f, 0.f, 0.f};

        #pragma unroll
        for (int kk = 0; kk < 8; ++kk) {
            uint4 av[8];
            #pragma unroll
            for (int mf = 0; mf < 8; ++mf) {
                if (mf < nMf) {
                    int prow = (int)(pa[mf] & 0xFFFFu);
                    int b = prow * 512 + ((kk * 64 + (lane >> 4) * 16) ^ ((prow & 7) << 4));
                    av[mf] = *(const uint4*)(Xw + b);
                }
            }
            #pragma unroll
            for (int n = 0; n < 4; ++n) {
                uint4 bv = *(const uint4*)(W1p + (size_t)(((kk * 16 + (w * 4 + n)) * 64 + lane) << 3));
                bf16x8 bf = __builtin_bit_cast(bf16x8, bv);
                #pragma unroll
                for (int mf = 0; mf < 8; ++mf)
                    if (mf < nMf)
                        acc1[mf][n] = __builtin_amdgcn_mfma_f32_16x16x32_bf16(
                            __builtin_bit_cast(bf16x8, av[mf]), bf, acc1[mf][n], 0, 0, 0);
            }
        }
        __syncthreads();   // all X reads done

        // (c) H write-back into the consumed pair bytes (guarded by sentinel)
        #pragma unroll
        for (int mf = 0; mf < 8; ++mf) {
            if (mf < nMf) {
                #pragma unroll
                for (int i = 0; i < 4; ++i) {
                    unsigned se = __shfl(pa[mf], (lane >> 4) * 4 + i, 64);
                    if ((se >> 16) != 0xFFFFu) {
                        int prow = (int)(se & 0xFFFFu);
                        int rbase = prow * 512, sm = (prow & 7) << 4;
                        #pragma unroll
                        for (int n = 0; n < 4; ++n) {
                            int c = (w * 4 + n) * 16 + (lane & 15);
                            float h = fmaxf(acc1[mf][n][i] + bb1[n], 0.f);
                            *(ushort*)(Xw + (rbase + ((c * 2) ^ sm))) = f2b(h);
                        }
                    }
                }
            }
        }
        __syncthreads();   // H visible

        // (d) GEMM2: Y = H @ W2 + b2, M split across waves (mf = w, w+4)
        f32x4 acc2[2][8];
        #pragma unroll
        for (int u = 0; u < 2; ++u)
            #pragma unroll
            for (int nt = 0; nt < 8; ++nt) acc2[u][nt] = f32x4{0.f, 0.f, 0.f, 0.f};

        #pragma unroll
        for (int kk = 0; kk < 8; ++kk) {
            uint4 av[2];
            #pragma unroll
            for (int u = 0; u < 2; ++u) {
                int mf = w + u * 4;
                if (mf < nMf) {
                    int prow = (int)(pa[mf] & 0xFFFFu);
                    int b = prow * 512 + ((kk * 64 + (lane >> 4) * 16) ^ ((prow & 7) << 4));
                    av[u] = *(const uint4*)(Xw + b);
                }
            }
            #pragma unroll
            for (int nt = 0; nt < 8; ++nt) {
                uint4 bv = *(const uint4*)(W2p + (size_t)(((kk * 8 + nt) * 64 + lane) << 3));
                bf16x8 bf = __builtin_bit_cast(bf16x8, bv);
                #pragma unroll
                for (int u = 0; u < 2; ++u)
                    if (w + u * 4 < nMf)
                        acc2[u][nt] = __builtin_amdgcn_mfma_f32_16x16x32_bf16(
                            __builtin_bit_cast(bf16x8, av[u]), bf, acc2[u][nt], 0, 0, 0);
            }
        }
        __syncthreads();   // all H reads done

        // (e) LayerNorm (in-register, 16-lane groups) + compacted Y write + leftover move
        #pragma unroll
        for (int u = 0; u < 2; ++u) {
            int mf = w + u * 4;
            if (mf < nMf) {
                float yv[8][4];
                float s1[4] = {0.f,0.f,0.f,0.f}, s2[4] = {0.f,0.f,0.f,0.f};
                #pragma unroll
                for (int nt = 0; nt < 8; ++nt)
                    #pragma unroll
                    for (int i = 0; i < 4; ++i) {
                        float v = acc2[u][nt][i] + bb2[nt];
                        yv[nt][i] = v; s1[i] += v; s2[i] += v * v;
                    }
                #pragma unroll
                for (int o = 1; o < 16; o <<= 1)
                    #pragma unroll
                    for (int i = 0; i < 4; ++i) {
                        s1[i] += __shfl_xor(s1[i], o, 64);
                        s2[i] += __shfl_xor(s2[i], o, 64);
                    }
                float mu[4], rs[4];
                #pragma unroll
                for (int i = 0; i < 4; ++i) {
                    mu[i] = s1[i] * (1.f / 128.f);
                    float var = s2[i] * (1.f / 128.f) - mu[i] * mu[i];
                    rs[i] = rsqrtf(var + 1e-5f);
                }
                #pragma unroll
                for (int i = 0; i < 4; ++i) {
                    unsigned se = __shfl(pa[mf], (lane >> 4) * 4 + i, 64);
                    int yd = (int)(se >> 16);
                    if (yd != 0xFFFF) {
                        #pragma unroll
                        for (int nt = 0; nt < 8; ++nt) {
                            int c = nt * 16 + (lane & 15);
                            float v = (yv[nt][i] - mu[i]) * rs[i] * lw[nt] + lb[nt];
                            *(ushort*)(Xw + swz(yd * 256 + c * 2)) = f2b(v);
                        }
                    }
                }
            }
        }
        // leftover rows: copy row (l-1) -> row 0 per odd item (disjoint from Y rows)
        #pragma unroll
        for (int q = 0; q < 4; ++q) {
            int it = q * 16 + (tid >> 4);
            if (it < G) {
                int srow = (int)cpS[it];
                if (srow != 0xFFFF) {
                    int ch = tid & 15;
                    uint4 v = *(const uint4*)(Xw + swz(srow * 256 + ch * 16));
                    *(uint4*)(Xw + swz((int)itOff[it] * 256 + ch * 16)) = v;
                }
            }
        }
        __syncthreads();
    }

    // ---- output: root = live row 0 of each item; L==1 exact f32 from args ----
    for (int j = tid; j < G * 32; j += 256) {
        int it = j >> 5, grp = j & 31;
        float4 o;
        if ((int)itL[it] == 1) {
            o = *(const float4*)(args + (size_t)itRow[it] * D + grp * 4);
        } else {
            uint2 v = *(const uint2*)(Xw + swz((int)itOff[it] * 256 + grp * 8));
            o.x = b2f((ushort)(v.x & 0xFFFFu));
            o.y = b2f((ushort)(v.x >> 16));
            o.z = b2f((ushort)(v.y & 0xFFFFu));
            o.w = b2f((ushort)(v.y >> 16));
        }
        *(float4*)(out + (size_t)itOut[it] * D + grp * 4) = o;
    }
}

// ---------------------------------------------------------------------------
extern "C" void kernel_launch(void* const* d_in, const int* in_sizes, int n_in,
                              void* d_out, int out_size, void* d_ws, size_t ws_size,
                              hipStream_t stream) {
    const float* args   = (const float*)d_in[0];
    const int*   limits = (const int*)d_in[1];     // harness: integer -> const int*
    const float* W1     = (const float*)d_in[2];
    const float* b1     = (const float*)d_in[3];
    const float* W2     = (const float*)d_in[4];
    const float* b2     = (const float*)d_in[5];
    const float* lnw    = (const float*)d_in[6];
    const float* lnb    = (const float*)d_in[7];

    char* ws = (char*)d_ws;
    ushort* W1p       = (ushort*)(ws);            // 131072 B
    ushort* W2p       = (ushort*)(ws + 131072);   //  65536 B
    ushort* sortedIdx = (ushort*)(ws + 196608);   //   1024 B
    ushort* offRows   = (ushort*)(ws + 197632);   //   1024 B
    ushort* binStart  = (ushort*)(ws + 198656);   //   1040 B (520 u16)
    int*    nbins     = (int*)   (ws + 199744);   //      4 B  -> total < 200 KB

    pack_w_kernel<<<384, 256, 0, stream>>>(W1, W2, W1p, W2p);
    plan_kernel<<<1, 512, 0, stream>>>(limits, sortedIdx, offRows, binStart, nbins);
    tree_kernel<<<512, 256, 0, stream>>>(args, limits, W1p, W2p, b1, b2, lnw, lnb,
                                         sortedIdx, offRows, binStart, nbins, (float*)d_out);
}

// Round 4
// 125.114 us; speedup vs baseline: 3.4083x; 3.4083x over previous
//
#include <hip/hip_runtime.h>
#include <stdint.h>

#define D 128
#define BB 512
#define NLEVELS 8

typedef __bf16 bf16x8 __attribute__((ext_vector_type(8)));
typedef float f32x4  __attribute__((ext_vector_type(4)));

__device__ __forceinline__ float b2f(ushort u) {
    uint x = ((uint)u) << 16;
    return __builtin_bit_cast(float, x);
}
__device__ __forceinline__ ushort f2b(float f) {   // round-to-nearest-even
    uint u = __builtin_bit_cast(uint, f);
    u += 0x7FFFu + ((u >> 16) & 1u);
    return (ushort)(u >> 16);
}
// swizzle: XOR low-3 bits of the 16B slot with the 512B pair-row index
__device__ __forceinline__ int swz(int b) { return b ^ (((b >> 9) & 7) << 4); }

// ---------------------------------------------------------------------------
// Weight packing (fragment-major bf16): W1p[((kk*16+nt)*64+lane)*8+t] =
//   W1[kk*32 + 8*(lane>>4) + t][nt*16 + (lane&15)]  (B-operand layout, 16x16x32)
// ---------------------------------------------------------------------------
__global__ void pack_w_kernel(const float* __restrict__ W1, const float* __restrict__ W2,
                              ushort* __restrict__ W1p, ushort* __restrict__ W2p) {
    int g = blockIdx.x * blockDim.x + threadIdx.x;
    if (g < 65536) {
        int t = g & 7, l = (g >> 3) & 63, nt = (g >> 9) & 15, kk = g >> 13;
        int krow = kk * 32 + (l >> 4) * 8 + t;
        int col  = nt * 16 + (l & 15);
        W1p[g] = f2b(W1[krow * 256 + col]);
    } else {
        int g2 = g - 65536;
        if (g2 < 32768) {
            int t = g2 & 7, l = (g2 >> 3) & 63, nt = (g2 >> 9) & 7, kk = g2 >> 12;
            int krow = kk * 32 + (l >> 4) * 8 + t;
            int col  = nt * 16 + (l & 15);
            W2p[g2] = f2b(W2[krow * 128 + col]);
        }
    }
}

// ---------------------------------------------------------------------------
// Block-wide inclusive scan (512 threads), u64 payload (multi-digit counters).
// ---------------------------------------------------------------------------
__device__ __forceinline__ unsigned long long block_scan_u64(unsigned long long v,
                                                             unsigned long long* wsum) {
    int lane = threadIdx.x & 63, wv = threadIdx.x >> 6;
    unsigned long long x = v;
    #pragma unroll
    for (int o = 1; o < 64; o <<= 1) {
        unsigned long long y = __shfl_up(x, (unsigned)o, 64);
        if (lane >= o) x += y;
    }
    if (lane == 63) wsum[wv] = x;
    __syncthreads();
    if (threadIdx.x == 0) {
        unsigned long long acc = 0;
        for (int i = 0; i < 8; ++i) { unsigned long long t = wsum[i]; wsum[i] = acc; acc += t; }
    }
    __syncthreads();
    unsigned long long r = x + wsum[wv];
    __syncthreads();
    return r;
}

// ---------------------------------------------------------------------------
// Plan: pow2-pad each item (min 4 rows), counting-sort by size descending
// (pow2 sizes never straddle a 256-row bin boundary), emit per-bin tables.
// NOTE: limits is int32 (harness converts integer inputs to int*).
// ---------------------------------------------------------------------------
__global__ void __launch_bounds__(512) plan_kernel(
    const int* __restrict__ limits,
    ushort* __restrict__ sortedIdx, ushort* __restrict__ offRows,
    ushort* __restrict__ binStart, int* __restrict__ nbinsOut)
{
    __shared__ unsigned long long wsum[8];
    __shared__ int cnt[16], base[16];
    __shared__ ushort p2a[512], sIdx[512], binA[512];
    const int tid = threadIdx.x;

    int Lm = limits[tid + 1] - limits[tid];
    Lm = min(max(Lm, 1), 256);            // defensive clamp
    int p2 = (Lm <= 1) ? 4 : (1 << (32 - __clz(Lm - 1)));
    if (p2 < 4) p2 = 4;
    int cls = 31 - __clz(p2);             // 2..8
    p2a[tid] = (ushort)p2;
    if (tid < 16) cnt[tid] = 0;
    __syncthreads();
    atomicAdd(&cnt[cls], 1);              // order-independent counts
    __syncthreads();
    if (tid == 0) {
        int b = 0;
        for (int c = 8; c >= 2; --c) { base[c] = b; b += cnt[c]; }
    }
    __syncthreads();

    // rank within class via multi-digit scans (16-bit digits, max 512 fits)
    unsigned long long va = (cls <= 5) ? (1ull << ((cls - 2) * 16)) : 0ull;
    unsigned long long vb = (cls >= 6) ? (1ull << ((cls - 6) * 16)) : 0ull;
    unsigned long long ia = block_scan_u64(va, wsum);
    unsigned long long ib = block_scan_u64(vb, wsum);
    int rank = (cls <= 5) ? (int)((ia >> ((cls - 2) * 16)) & 0xFFFF) - 1
                          : (int)((ib >> ((cls - 6) * 16)) & 0xFFFF) - 1;
    int pos = base[cls] + rank;
    sIdx[pos] = (ushort)tid;
    __syncthreads();

    // padded cumsum in sorted order
    unsigned long long pv = (unsigned long long)p2a[sIdx[tid]];
    unsigned long long ic = block_scan_u64(pv, wsum);
    unsigned int cumB = (unsigned int)(ic - pv);
    int bin = (int)(cumB >> 8);
    binA[tid] = (ushort)bin;
    sortedIdx[tid] = sIdx[tid];
    offRows[tid]  = (ushort)(cumB & 255);
    __syncthreads();
    if (tid == 0) binStart[0] = 0;
    else if (binA[tid] != binA[tid - 1]) binStart[bin] = (ushort)tid;
    if (tid == 511) { nbinsOut[0] = bin + 1; binStart[bin + 1] = 512; }
}

// ---------------------------------------------------------------------------
// Fused tree kernel v2: one block (512 thr / 8 waves) = one bin.
// W1 resident in REGISTERS (N-split 8: 2 frag-cols/wave), W2 resident in LDS.
// Level loop touches only LDS + registers: sched -> GEMM1(N-split)+ReLU ->
// GEMM2(M-split, W2 from LDS)+LN -> compaction, in one 64KB X buffer.
// ---------------------------------------------------------------------------
__global__ void __launch_bounds__(512, 2) tree_kernel(
    const float* __restrict__ args, const int* __restrict__ limits,
    const ushort* __restrict__ W1p, const ushort* __restrict__ W2p,
    const float* __restrict__ b1, const float* __restrict__ b2,
    const float* __restrict__ lnw, const float* __restrict__ lnb,
    const ushort* __restrict__ sortedIdx, const ushort* __restrict__ offRows,
    const ushort* __restrict__ binStart, const int* __restrict__ nbinsP,
    float* __restrict__ out)
{
    if ((int)blockIdx.x >= *nbinsP) return;

    __shared__ __align__(16) char Xw[65536];
    __shared__ __align__(16) char W2s[65536];
    __shared__ unsigned int sched[128];
    __shared__ ushort itOff[64], itL[64], itCur[64], itOut[64], itYb[64], cpS[64];
    __shared__ ushort startP[65];
    __shared__ int itRow[64];
    __shared__ int rowsrc[256];
    __shared__ int gmisc[4];   // 0:G  1:nlev  2:nP

    const int tid = threadIdx.x, lane = tid & 63, w = tid >> 6;

    if (tid == 0) gmisc[0] = (int)binStart[blockIdx.x + 1] - (int)binStart[blockIdx.x];
    __syncthreads();
    const int G = gmisc[0];

    if (tid < G) {
        int pos = (int)binStart[blockIdx.x] + tid;
        int it = sortedIdx[pos];
        itOff[tid] = offRows[pos];
        int a0 = limits[it];
        int Lm = limits[it + 1] - a0;
        Lm = min(max(Lm, 1), 256);
        itL[tid] = (ushort)Lm; itCur[tid] = (ushort)Lm;
        itRow[tid] = a0;  itOut[tid] = (ushort)it;
    }
    if (tid < 64) {
        int lev = 0;
        if (tid < G) { int Lm = (int)itL[tid]; lev = (Lm > 1) ? (32 - __clz(Lm - 1)) : 0; }
        #pragma unroll
        for (int o = 32; o; o >>= 1) lev = max(lev, __shfl_xor(lev, o, 64));
        if (tid == 0) gmisc[1] = lev;
    }

    // ---- W1 slice -> registers (wave w owns frag-cols w*2, w*2+1), once ----
    uint4 w1r[8][2];
    #pragma unroll
    for (int kk = 0; kk < 8; ++kk)
        #pragma unroll
        for (int n = 0; n < 2; ++n)
            w1r[kk][n] = *(const uint4*)(W1p + (size_t)(((kk * 16 + (w * 2 + n)) * 64 + lane) << 3));

    // per-lane constant epilogue params
    float bb1[2], bb2[8], lw[8], lb[8];
    #pragma unroll
    for (int n = 0; n < 2; ++n) bb1[n] = b1[(w * 2 + n) * 16 + (lane & 15)];
    #pragma unroll
    for (int nt = 0; nt < 8; ++nt) {
        int c = nt * 16 + (lane & 15);
        bb2[nt] = b2[c]; lw[nt] = lnw[c]; lb[nt] = lnb[c];
    }

    // ---- W2 packed -> LDS (64KB), once ----
    #pragma unroll
    for (int q = 0; q < 8; ++q) {
        int t = tid + q * 512;
        *(uint4*)(W2s + t * 16) = *(const uint4*)((const char*)W2p + t * 16);
    }

    __syncthreads();   // itOff/itL valid
    const int nlev = gmisc[1];

    // ---- rowsrc map + leaf staging (f32 -> bf16, swizzled ds_write) ----
    if (tid < 256) {
        int r = tid;
        int lo = 0, hi = G;
        while (hi - lo > 1) { int mid = (lo + hi) >> 1; if ((int)itOff[mid] <= r) lo = mid; else hi = mid; }
        int rel = r - (int)itOff[lo];
        rowsrc[r] = (rel >= 0 && rel < (int)itL[lo]) ? (itRow[lo] + rel) : -1;
    }
    __syncthreads();
    #pragma unroll
    for (int q = 0; q < 8; ++q) {
        int job = tid + q * 512;
        int r = job >> 4, ch = job & 15;
        int src = rowsrc[r];
        if (src >= 0) {
            const float4 f0 = *(const float4*)(args + (size_t)src * D + ch * 8);
            const float4 f1 = *(const float4*)(args + (size_t)src * D + ch * 8 + 4);
            uint4 pk;
            pk.x = (uint)f2b(f0.x) | ((uint)f2b(f0.y) << 16);
            pk.y = (uint)f2b(f0.z) | ((uint)f2b(f0.w) << 16);
            pk.z = (uint)f2b(f1.x) | ((uint)f2b(f1.y) << 16);
            pk.w = (uint)f2b(f1.z) | ((uint)f2b(f1.w) << 16);
            *(uint4*)(Xw + swz(r * 256 + ch * 16)) = pk;
        }
    }
    __syncthreads();

    // ---- level loop ----
    for (int k = 0; k < nlev; ++k) {
        // (a) schedule generation (wave 0 does item math)
        if (tid < 64) {
            int l = (tid < G) ? (int)itCur[tid] : 0;
            int p = l >> 1;
            int x = p;
            #pragma unroll
            for (int o = 1; o < 64; o <<= 1) { int y = __shfl_up(x, (unsigned)o, 64); if (lane >= o) x += y; }
            int excl = x - p;
            if (tid < G) {
                startP[tid] = (ushort)excl;
                itYb[tid]   = (ushort)((int)itOff[tid] + (l & 1));
                cpS[tid]    = (l > 1 && (l & 1)) ? (ushort)((int)itOff[tid] + l - 1) : (ushort)0xFFFF;
                itCur[tid]  = (ushort)(p + (l & 1));
            }
            if (tid == 63) gmisc[2] = x;
        }
        __syncthreads();
        const int nP = gmisc[2];
        if (nP == 0) break;
        const int nMf = (nP + 15) >> 4;
        const int nPpad = nMf << 4;
        if (tid < nPpad) {
            unsigned int entry;
            if (tid < nP) {
                int lo = 0, hi = G;
                while (hi - lo > 1) { int mid = (lo + hi) >> 1; if ((int)startP[mid] <= tid) lo = mid; else hi = mid; }
                int j = tid - (int)startP[lo];
                entry = (unsigned)(((int)itOff[lo] >> 1) + j) | ((unsigned)((int)itYb[lo] + j) << 16);
            } else {
                entry = 0u | (0xFFFFu << 16);
            }
            sched[tid] = entry;
        }
        __syncthreads();

        // per-lane schedule fragments (prow for pairIdx = mf*16 + (lane&15))
        unsigned int pa[8];
        #pragma unroll
        for (int mf = 0; mf < 8; ++mf)
            pa[mf] = (mf < nMf) ? sched[mf * 16 + (lane & 15)] : (0xFFFFu << 16);

        // (b) GEMM1: H = relu(X @ W1 + b1); N-split: wave w -> cols [w*32, w*32+32)
        f32x4 acc1[8][2];
        #pragma unroll
        for (int mf = 0; mf < 8; ++mf)
            #pragma unroll
            for (int n = 0; n < 2; ++n) acc1[mf][n] = f32x4{0.f, 0.f, 0.f, 0.f};

        #pragma unroll
        for (int kk = 0; kk < 8; ++kk) {
            uint4 av[8];
            #pragma unroll
            for (int mf = 0; mf < 8; ++mf) {
                if (mf < nMf) {
                    int prow = (int)(pa[mf] & 0xFFFFu);
                    int b = prow * 512 + ((kk * 64 + (lane >> 4) * 16) ^ ((prow & 7) << 4));
                    av[mf] = *(const uint4*)(Xw + b);
                }
            }
            #pragma unroll
            for (int n = 0; n < 2; ++n) {
                bf16x8 bf = __builtin_bit_cast(bf16x8, w1r[kk][n]);
                #pragma unroll
                for (int mf = 0; mf < 8; ++mf)
                    if (mf < nMf)
                        acc1[mf][n] = __builtin_amdgcn_mfma_f32_16x16x32_bf16(
                            __builtin_bit_cast(bf16x8, av[mf]), bf, acc1[mf][n], 0, 0, 0);
            }
        }
        __syncthreads();   // all X reads done

        // (c) H write-back into the consumed pair bytes (wave's 32 cols, all rows)
        #pragma unroll
        for (int mf = 0; mf < 8; ++mf) {
            if (mf < nMf) {
                #pragma unroll
                for (int i = 0; i < 4; ++i) {
                    unsigned se = __shfl(pa[mf], (lane >> 4) * 4 + i, 64);
                    if ((se >> 16) != 0xFFFFu) {
                        int prow = (int)(se & 0xFFFFu);
                        int rbase = prow * 512, sm = (prow & 7) << 4;
                        #pragma unroll
                        for (int n = 0; n < 2; ++n) {
                            int c = (w * 2 + n) * 16 + (lane & 15);
                            float h = fmaxf(acc1[mf][n][i] + bb1[n], 0.f);
                            *(ushort*)(Xw + (rbase + ((c * 2) ^ sm))) = f2b(h);
                        }
                    }
                }
            }
        }
        __syncthreads();   // H visible

        // (d) GEMM2: Y = H @ W2 + b2; M-split: wave w -> fragment mf = w
        f32x4 acc2[8];
        #pragma unroll
        for (int nt = 0; nt < 8; ++nt) acc2[nt] = f32x4{0.f, 0.f, 0.f, 0.f};

        if (w < nMf) {
            int prow = (int)(sched[w * 16 + (lane & 15)] & 0xFFFFu);
            int sm = (prow & 7) << 4, rbase = prow * 512;
            #pragma unroll
            for (int kk = 0; kk < 8; ++kk) {
                uint4 av = *(const uint4*)(Xw + (rbase + ((kk * 64 + (lane >> 4) * 16) ^ sm)));
                bf16x8 af = __builtin_bit_cast(bf16x8, av);
                #pragma unroll
                for (int nt = 0; nt < 8; ++nt) {
                    uint4 bv = *(const uint4*)(W2s + (((kk * 8 + nt) * 64 + lane) << 4));
                    acc2[nt] = __builtin_amdgcn_mfma_f32_16x16x32_bf16(
                        af, __builtin_bit_cast(bf16x8, bv), acc2[nt], 0, 0, 0);
                }
            }
        }
        __syncthreads();   // all H reads done

        // (e) LayerNorm (in-register, 16-lane groups) + compacted Y write
        if (w < nMf) {
            float yv[8][4];
            float s1[4] = {0.f,0.f,0.f,0.f}, s2[4] = {0.f,0.f,0.f,0.f};
            #pragma unroll
            for (int nt = 0; nt < 8; ++nt)
                #pragma unroll
                for (int i = 0; i < 4; ++i) {
                    float v = acc2[nt][i] + bb2[nt];
                    yv[nt][i] = v; s1[i] += v; s2[i] += v * v;
                }
            #pragma unroll
            for (int o = 1; o < 16; o <<= 1)
                #pragma unroll
                for (int i = 0; i < 4; ++i) {
                    s1[i] += __shfl_xor(s1[i], o, 64);
                    s2[i] += __shfl_xor(s2[i], o, 64);
                }
            float mu[4], rs[4];
            #pragma unroll
            for (int i = 0; i < 4; ++i) {
                mu[i] = s1[i] * (1.f / 128.f);
                float var = s2[i] * (1.f / 128.f) - mu[i] * mu[i];
                rs[i] = rsqrtf(var + 1e-5f);
            }
            #pragma unroll
            for (int i = 0; i < 4; ++i) {
                unsigned se = sched[w * 16 + (lane >> 4) * 4 + i];
                int yd = (int)(se >> 16);
                if (yd != 0xFFFF) {
                    #pragma unroll
                    for (int nt = 0; nt < 8; ++nt) {
                        int c = nt * 16 + (lane & 15);
                        float v = (yv[nt][i] - mu[i]) * rs[i] * lw[nt] + lb[nt];
                        *(ushort*)(Xw + swz(yd * 256 + c * 2)) = f2b(v);
                    }
                }
            }
        }
        // leftover rows: copy row (l-1) -> row 0 per odd item (disjoint from Y rows)
        #pragma unroll
        for (int q = 0; q < 2; ++q) {
            int it = q * 32 + (tid >> 4);
            if (it < G) {
                int srow = (int)cpS[it];
                if (srow != 0xFFFF) {
                    int ch = tid & 15;
                    uint4 v = *(const uint4*)(Xw + swz(srow * 256 + ch * 16));
                    *(uint4*)(Xw + swz((int)itOff[it] * 256 + ch * 16)) = v;
                }
            }
        }
        __syncthreads();
    }

    // ---- output: root = live row 0 of each item; L==1 exact f32 from args ----
    for (int j = tid; j < G * 32; j += 512) {
        int it = j >> 5, grp = j & 31;
        float4 o;
        if ((int)itL[it] == 1) {
            o = *(const float4*)(args + (size_t)itRow[it] * D + grp * 4);
        } else {
            uint2 v = *(const uint2*)(Xw + swz((int)itOff[it] * 256 + grp * 8));
            o.x = b2f((ushort)(v.x & 0xFFFFu));
            o.y = b2f((ushort)(v.x >> 16));
            o.z = b2f((ushort)(v.y & 0xFFFFu));
            o.w = b2f((ushort)(v.y >> 16));
        }
        *(float4*)(out + (size_t)itOut[it] * D + grp * 4) = o;
    }
}

// ---------------------------------------------------------------------------
extern "C" void kernel_launch(void* const* d_in, const int* in_sizes, int n_in,
                              void* d_out, int out_size, void* d_ws, size_t ws_size,
                              hipStream_t stream) {
    const float* args   = (const float*)d_in[0];
    const int*   limits = (const int*)d_in[1];     // harness: integer -> const int*
    const float* W1     = (const float*)d_in[2];
    const float* b1     = (const float*)d_in[3];
    const float* W2     = (const float*)d_in[4];
    const float* b2     = (const float*)d_in[5];
    const float* lnw    = (const float*)d_in[6];
    const float* lnb    = (const float*)d_in[7];

    char* ws = (char*)d_ws;
    ushort* W1p       = (ushort*)(ws);            // 131072 B
    ushort* W2p       = (ushort*)(ws + 131072);   //  65536 B
    ushort* sortedIdx = (ushort*)(ws + 196608);   //   1024 B
    ushort* offRows   = (ushort*)(ws + 197632);   //   1024 B
    ushort* binStart  = (ushort*)(ws + 198656);   //   1040 B (520 u16)
    int*    nbins     = (int*)   (ws + 199744);   //      4 B  -> total < 200 KB

    pack_w_kernel<<<384, 256, 0, stream>>>(W1, W2, W1p, W2p);
    plan_kernel<<<1, 512, 0, stream>>>(limits, sortedIdx, offRows, binStart, nbins);
    tree_kernel<<<512, 512, 0, stream>>>(args, limits, W1p, W2p, b1, b2, lnw, lnb,
                                         sortedIdx, offRows, binStart, nbins, (float*)d_out);
}

// Round 5
// 123.964 us; speedup vs baseline: 3.4399x; 1.0093x over previous
//
#include <hip/hip_runtime.h>
#include <stdint.h>

#define D 128
#define BB 512
#define NLEVELS 8

typedef __bf16 bf16x8 __attribute__((ext_vector_type(8)));
typedef float f32x4  __attribute__((ext_vector_type(4)));

__device__ __forceinline__ float b2f(ushort u) {
    uint x = ((uint)u) << 16;
    return __builtin_bit_cast(float, x);
}
__device__ __forceinline__ ushort f2b(float f) {   // round-to-nearest-even
    uint u = __builtin_bit_cast(uint, f);
    u += 0x7FFFu + ((u >> 16) & 1u);
    return (ushort)(u >> 16);
}
// swizzle: XOR low-3 bits of the 16B slot with the 512B pair-row index
__device__ __forceinline__ int swz(int b) { return b ^ (((b >> 9) & 7) << 4); }

// ---------------------------------------------------------------------------
// Weight packing (fragment-major bf16): W1p[((kk*16+nt)*64+lane)*8+t] =
//   W1[kk*32 + 8*(lane>>4) + t][nt*16 + (lane&15)]  (B-operand layout, 16x16x32)
// ---------------------------------------------------------------------------
__global__ void pack_w_kernel(const float* __restrict__ W1, const float* __restrict__ W2,
                              ushort* __restrict__ W1p, ushort* __restrict__ W2p) {
    int g = blockIdx.x * blockDim.x + threadIdx.x;
    if (g < 65536) {
        int t = g & 7, l = (g >> 3) & 63, nt = (g >> 9) & 15, kk = g >> 13;
        int krow = kk * 32 + (l >> 4) * 8 + t;
        int col  = nt * 16 + (l & 15);
        W1p[g] = f2b(W1[krow * 256 + col]);
    } else {
        int g2 = g - 65536;
        if (g2 < 32768) {
            int t = g2 & 7, l = (g2 >> 3) & 63, nt = (g2 >> 9) & 7, kk = g2 >> 12;
            int krow = kk * 32 + (l >> 4) * 8 + t;
            int col  = nt * 16 + (l & 15);
            W2p[g2] = f2b(W2[krow * 128 + col]);
        }
    }
}

// ---------------------------------------------------------------------------
// Block-wide inclusive scan (512 threads), u64 payload (multi-digit counters).
// ---------------------------------------------------------------------------
__device__ __forceinline__ unsigned long long block_scan_u64(unsigned long long v,
                                                             unsigned long long* wsum) {
    int lane = threadIdx.x & 63, wv = threadIdx.x >> 6;
    unsigned long long x = v;
    #pragma unroll
    for (int o = 1; o < 64; o <<= 1) {
        unsigned long long y = __shfl_up(x, (unsigned)o, 64);
        if (lane >= o) x += y;
    }
    if (lane == 63) wsum[wv] = x;
    __syncthreads();
    if (threadIdx.x == 0) {
        unsigned long long acc = 0;
        for (int i = 0; i < 8; ++i) { unsigned long long t = wsum[i]; wsum[i] = acc; acc += t; }
    }
    __syncthreads();
    unsigned long long r = x + wsum[wv];
    __syncthreads();
    return r;
}

// ---------------------------------------------------------------------------
// Plan: pow2-pad each item (min 4 rows), counting-sort by size descending
// (pow2 sizes never straddle a 256-row bin boundary), emit per-bin tables.
// NOTE: limits is int32 (harness converts integer inputs to int*).
// ---------------------------------------------------------------------------
__global__ void __launch_bounds__(512) plan_kernel(
    const int* __restrict__ limits,
    ushort* __restrict__ sortedIdx, ushort* __restrict__ offRows,
    ushort* __restrict__ binStart, int* __restrict__ nbinsOut)
{
    __shared__ unsigned long long wsum[8];
    __shared__ int cnt[16], base[16];
    __shared__ ushort p2a[512], sIdx[512], binA[512];
    const int tid = threadIdx.x;

    int Lm = limits[tid + 1] - limits[tid];
    Lm = min(max(Lm, 1), 256);            // defensive clamp
    int p2 = (Lm <= 1) ? 4 : (1 << (32 - __clz(Lm - 1)));
    if (p2 < 4) p2 = 4;
    int cls = 31 - __clz(p2);             // 2..8
    p2a[tid] = (ushort)p2;
    if (tid < 16) cnt[tid] = 0;
    __syncthreads();
    atomicAdd(&cnt[cls], 1);              // order-independent counts
    __syncthreads();
    if (tid == 0) {
        int b = 0;
        for (int c = 8; c >= 2; --c) { base[c] = b; b += cnt[c]; }
    }
    __syncthreads();

    // rank within class via multi-digit scans (16-bit digits, max 512 fits)
    unsigned long long va = (cls <= 5) ? (1ull << ((cls - 2) * 16)) : 0ull;
    unsigned long long vb = (cls >= 6) ? (1ull << ((cls - 6) * 16)) : 0ull;
    unsigned long long ia = block_scan_u64(va, wsum);
    unsigned long long ib = block_scan_u64(vb, wsum);
    int rank = (cls <= 5) ? (int)((ia >> ((cls - 2) * 16)) & 0xFFFF) - 1
                          : (int)((ib >> ((cls - 6) * 16)) & 0xFFFF) - 1;
    int pos = base[cls] + rank;
    sIdx[pos] = (ushort)tid;
    __syncthreads();

    // padded cumsum in sorted order
    unsigned long long pv = (unsigned long long)p2a[sIdx[tid]];
    unsigned long long ic = block_scan_u64(pv, wsum);
    unsigned int cumB = (unsigned int)(ic - pv);
    int bin = (int)(cumB >> 8);
    binA[tid] = (ushort)bin;
    sortedIdx[tid] = sIdx[tid];
    offRows[tid]  = (ushort)(cumB & 255);
    __syncthreads();
    if (tid == 0) binStart[0] = 0;
    else if (binA[tid] != binA[tid - 1]) binStart[bin] = (ushort)tid;
    if (tid == 511) { nbinsOut[0] = bin + 1; binStart[bin + 1] = 512; }
}

// ---------------------------------------------------------------------------
// Fused tree kernel v3: persistent blocks (grid 256), each walks bins
// bin = blockIdx.x + 256*i. One bin = <=64 items, <=256 live rows in LDS.
// W1 in registers; W2 in LDS (staged once per block). All levels' pair
// schedules precomputed up front (wave 0) overlapped with leaf staging.
// GEMM1 operand-SWAPPED: acc = mfma(A=W1-frag, B=X-row-frag) computes H^T,
// so each lane holds 4 consecutive H columns -> packed ds_write_b64, no
// shuffles. 4 barriers per level.
// ---------------------------------------------------------------------------
__global__ void __launch_bounds__(512, 2) tree_kernel(
    const float* __restrict__ args, const int* __restrict__ limits,
    const ushort* __restrict__ W1p, const ushort* __restrict__ W2p,
    const float* __restrict__ b1, const float* __restrict__ b2,
    const float* __restrict__ lnw, const float* __restrict__ lnb,
    const ushort* __restrict__ sortedIdx, const ushort* __restrict__ offRows,
    const ushort* __restrict__ binStart, const int* __restrict__ nbinsP,
    float* __restrict__ out)
{
    __shared__ __align__(16) char Xw[65536];
    __shared__ __align__(16) char W2s[65536];
    __shared__ unsigned int schedAll[1024];     // 8 levels x 128 entries
    __shared__ ushort cpSAll[8][64];
    __shared__ ushort itOff[64], itL[64], itOut[64], startP[64], ybS[64];
    __shared__ int itRow[64];
    __shared__ int nPAll[8];
    __shared__ int gmisc[2];   // 0:G  1:nlev

    const int tid = threadIdx.x, lane = tid & 63, w = tid >> 6;
    const int nbins = *nbinsP;

    // ---- one-time per block: W1 slice -> regs (wave w owns cols 32w..32w+32)
    uint4 w1r[8][2];
    #pragma unroll
    for (int kk = 0; kk < 8; ++kk)
        #pragma unroll
        for (int n = 0; n < 2; ++n)
            w1r[kk][n] = *(const uint4*)(W1p + (size_t)(((kk * 16 + (w * 2 + n)) * 64 + lane) << 3));

    // epilogue constants. GEMM1 (swapped) lane holds H cols 32w+16n+4*(lane>>4)+i
    float bb1[2][4];
    #pragma unroll
    for (int n = 0; n < 2; ++n)
        #pragma unroll
        for (int i = 0; i < 4; ++i)
            bb1[n][i] = b1[32 * w + 16 * n + 4 * (lane >> 4) + i];
    float bb2[8], lw[8], lb[8];
    #pragma unroll
    for (int nt = 0; nt < 8; ++nt) {
        int c = nt * 16 + (lane & 15);
        bb2[nt] = b2[c]; lw[nt] = lnw[c]; lb[nt] = lnb[c];
    }

    // ---- one-time per block: W2 packed -> LDS (64KB)
    #pragma unroll
    for (int q = 0; q < 8; ++q) {
        int t = tid + q * 512;
        *(uint4*)(W2s + t * 16) = *(const uint4*)((const char*)W2p + t * 16);
    }

    for (int bin = blockIdx.x; bin < nbins; bin += gridDim.x) {
        __syncthreads();   // previous bin's LDS readers done
        if (tid == 0) gmisc[0] = (int)binStart[bin + 1] - (int)binStart[bin];
        __syncthreads();
        const int G = gmisc[0];

        if (tid < G) {
            int pos = (int)binStart[bin] + tid;
            int it = sortedIdx[pos];
            itOff[tid] = offRows[pos];
            int a0 = limits[it];
            int Lm = min(max(limits[it + 1] - a0, 1), 256);
            itL[tid] = (ushort)Lm;
            itRow[tid] = a0; itOut[tid] = (ushort)it;
        }
        if (tid < 64) {
            int lev = 0;
            if (tid < G) { int Lm = (int)itL[tid]; lev = (Lm > 1) ? (32 - __clz(Lm - 1)) : 0; }
            #pragma unroll
            for (int o = 32; o; o >>= 1) lev = max(lev, __shfl_xor(lev, o, 64));
            if (tid == 0) gmisc[1] = lev;
        }
        __syncthreads();
        const int nlev = gmisc[1];

        if (w == 0) {
            // ---- all-level schedule precompute (data-independent) ----
            int l   = (lane < G) ? (int)itL[lane] : 0;
            int off = (lane < G) ? (int)itOff[lane] : 0;
            for (int k = 0; k < nlev; ++k) {
                int p = l >> 1;
                int x = p;
                #pragma unroll
                for (int o = 1; o < 64; o <<= 1) { int y = __shfl_up(x, (unsigned)o, 64); if (lane >= o) x += y; }
                startP[lane] = (ushort)(x - p);
                ybS[lane]    = (ushort)(off + (l & 1));
                cpSAll[k][lane] = (l > 1 && (l & 1)) ? (ushort)(off + l - 1) : (ushort)0xFFFF;
                int nPk = __shfl(x, 63, 64);
                if (lane == 0) nPAll[k] = nPk;
                #pragma unroll
                for (int rep = 0; rep < 2; ++rep) {
                    int e = lane + rep * 64;
                    unsigned entry = 0xFFFF0000u;
                    if (e < nPk) {
                        int lo = 0, hi = G;
                        while (hi - lo > 1) { int mid = (lo + hi) >> 1; if ((int)startP[mid] <= e) lo = mid; else hi = mid; }
                        int j = e - (int)startP[lo];
                        entry = (unsigned)(((int)itOff[lo] >> 1) + j) | ((unsigned)((int)ybS[lo] + j) << 16);
                    }
                    schedAll[k * 128 + e] = entry;
                }
                l = p + (l & 1);
            }
        } else {
            // ---- leaf staging by waves 1..7 (f32 -> bf16, swizzled) ----
            for (int job = tid - 64; job < 4096; job += 448) {
                int r = job >> 4, ch = job & 15;
                int lo = 0, hi = G;
                while (hi - lo > 1) { int mid = (lo + hi) >> 1; if ((int)itOff[mid] <= r) lo = mid; else hi = mid; }
                int rel = r - (int)itOff[lo];
                if (rel >= 0 && rel < (int)itL[lo]) {
                    int src = itRow[lo] + rel;
                    const float4 f0 = *(const float4*)(args + (size_t)src * D + ch * 8);
                    const float4 f1 = *(const float4*)(args + (size_t)src * D + ch * 8 + 4);
                    uint4 pk;
                    pk.x = (uint)f2b(f0.x) | ((uint)f2b(f0.y) << 16);
                    pk.y = (uint)f2b(f0.z) | ((uint)f2b(f0.w) << 16);
                    pk.z = (uint)f2b(f1.x) | ((uint)f2b(f1.y) << 16);
                    pk.w = (uint)f2b(f1.z) | ((uint)f2b(f1.w) << 16);
                    *(uint4*)(Xw + swz(r * 256 + ch * 16)) = pk;
                }
            }
        }
        __syncthreads();

        // ---- level loop (4 barriers per level) ----
        for (int k = 0; k < nlev; ++k) {
            const int nP  = nPAll[k];
            const int nMf = (nP + 15) >> 4;
            const unsigned* sk = schedAll + k * 128;

            unsigned pa[8];
            #pragma unroll
            for (int mf = 0; mf < 8; ++mf)
                pa[mf] = sk[mf * 16 + (lane & 15)];

            // (b) GEMM1 swapped: acc1[n][mf] = H^T fragment (rows=cols c, cols=pairs p)
            f32x4 acc1[2][8];
            #pragma unroll
            for (int n = 0; n < 2; ++n)
                #pragma unroll
                for (int mf = 0; mf < 8; ++mf) acc1[n][mf] = f32x4{0.f, 0.f, 0.f, 0.f};

            #pragma unroll
            for (int kk = 0; kk < 8; ++kk) {
                uint4 xv[8];
                #pragma unroll
                for (int mf = 0; mf < 8; ++mf) {
                    if (mf < nMf) {
                        int prow = (int)(pa[mf] & 0xFFFFu);
                        int b = prow * 512 + ((kk * 64 + (lane >> 4) * 16) ^ ((prow & 7) << 4));
                        xv[mf] = *(const uint4*)(Xw + b);
                    }
                }
                #pragma unroll
                for (int n = 0; n < 2; ++n) {
                    bf16x8 af = __builtin_bit_cast(bf16x8, w1r[kk][n]);
                    #pragma unroll
                    for (int mf = 0; mf < 8; ++mf)
                        if (mf < nMf)
                            acc1[n][mf] = __builtin_amdgcn_mfma_f32_16x16x32_bf16(
                                af, __builtin_bit_cast(bf16x8, xv[mf]), acc1[n][mf], 0, 0, 0);
                }
            }
            __syncthreads();   // all X reads done

            // (c) H write-back: lane holds 4 consecutive cols of row p -> b64 writes
            #pragma unroll
            for (int mf = 0; mf < 8; ++mf) {
                if (mf < nMf && (pa[mf] >> 16) != 0xFFFFu) {
                    int prow = (int)(pa[mf] & 0xFFFFu);
                    int rbase = prow * 512, sm = (prow & 7) << 4;
                    #pragma unroll
                    for (int n = 0; n < 2; ++n) {
                        float h0 = fmaxf(acc1[n][mf][0] + bb1[n][0], 0.f);
                        float h1 = fmaxf(acc1[n][mf][1] + bb1[n][1], 0.f);
                        float h2 = fmaxf(acc1[n][mf][2] + bb1[n][2], 0.f);
                        float h3 = fmaxf(acc1[n][mf][3] + bb1[n][3], 0.f);
                        uint2 pk;
                        pk.x = (uint)f2b(h0) | ((uint)f2b(h1) << 16);
                        pk.y = (uint)f2b(h2) | ((uint)f2b(h3) << 16);
                        *(uint2*)(Xw + (rbase + ((64 * w + 32 * n + 8 * (lane >> 4)) ^ sm))) = pk;
                    }
                }
            }
            __syncthreads();   // H visible

            // (d) GEMM2: Y = H @ W2 + b2; M-split: wave w -> pair fragment w
            f32x4 acc2[8];
            #pragma unroll
            for (int nt = 0; nt < 8; ++nt) acc2[nt] = f32x4{0.f, 0.f, 0.f, 0.f};

            if (w < nMf) {
                int prow = (int)(sk[w * 16 + (lane & 15)] & 0xFFFFu);
                int sm = (prow & 7) << 4, rbase = prow * 512;
                #pragma unroll
                for (int kk = 0; kk < 8; ++kk) {
                    uint4 av = *(const uint4*)(Xw + (rbase + ((kk * 64 + (lane >> 4) * 16) ^ sm)));
                    bf16x8 af = __builtin_bit_cast(bf16x8, av);
                    #pragma unroll
                    for (int nt = 0; nt < 8; ++nt) {
                        uint4 bv = *(const uint4*)(W2s + (((kk * 8 + nt) * 64 + lane) << 4));
                        acc2[nt] = __builtin_amdgcn_mfma_f32_16x16x32_bf16(
                            af, __builtin_bit_cast(bf16x8, bv), acc2[nt], 0, 0, 0);
                    }
                }
            }
            __syncthreads();   // all H reads done

            // (e) LayerNorm + compacted Y write
            if (w < nMf) {
                float yv[8][4];
                float s1[4] = {0.f,0.f,0.f,0.f}, s2[4] = {0.f,0.f,0.f,0.f};
                #pragma unroll
                for (int nt = 0; nt < 8; ++nt)
                    #pragma unroll
                    for (int i = 0; i < 4; ++i) {
                        float v = acc2[nt][i] + bb2[nt];
                        yv[nt][i] = v; s1[i] += v; s2[i] += v * v;
                    }
                #pragma unroll
                for (int o = 1; o < 16; o <<= 1)
                    #pragma unroll
                    for (int i = 0; i < 4; ++i) {
                        s1[i] += __shfl_xor(s1[i], o, 64);
                        s2[i] += __shfl_xor(s2[i], o, 64);
                    }
                float mu[4], rs[4];
                #pragma unroll
                for (int i = 0; i < 4; ++i) {
                    mu[i] = s1[i] * (1.f / 128.f);
                    float var = s2[i] * (1.f / 128.f) - mu[i] * mu[i];
                    rs[i] = rsqrtf(var + 1e-5f);
                }
                #pragma unroll
                for (int i = 0; i < 4; ++i) {
                    unsigned se = sk[w * 16 + (lane >> 4) * 4 + i];
                    int yd = (int)(se >> 16);
                    if (yd != 0xFFFF) {
                        #pragma unroll
                        for (int nt = 0; nt < 8; ++nt) {
                            int c = nt * 16 + (lane & 15);
                            float v = (yv[nt][i] - mu[i]) * rs[i] * lw[nt] + lb[nt];
                            *(ushort*)(Xw + swz(yd * 256 + c * 2)) = f2b(v);
                        }
                    }
                }
            }
            // leftover rows: copy row (l-1) -> row itOff per odd item (disjoint from Y rows)
            #pragma unroll
            for (int q = 0; q < 2; ++q) {
                int it = q * 32 + (tid >> 4);
                if (it < G) {
                    int srow = (int)cpSAll[k][it];
                    if (srow != 0xFFFF) {
                        int ch = tid & 15;
                        uint4 v = *(const uint4*)(Xw + swz(srow * 256 + ch * 16));
                        *(uint4*)(Xw + swz((int)itOff[it] * 256 + ch * 16)) = v;
                    }
                }
            }
            __syncthreads();
        }

        // ---- output: root = live row itOff of each item; L==1 exact f32 ----
        for (int j = tid; j < G * 32; j += 512) {
            int it = j >> 5, grp = j & 31;
            float4 o;
            if ((int)itL[it] == 1) {
                o = *(const float4*)(args + (size_t)itRow[it] * D + grp * 4);
            } else {
                uint2 v = *(const uint2*)(Xw + swz((int)itOff[it] * 256 + grp * 8));
                o.x = b2f((ushort)(v.x & 0xFFFFu));
                o.y = b2f((ushort)(v.x >> 16));
                o.z = b2f((ushort)(v.y & 0xFFFFu));
                o.w = b2f((ushort)(v.y >> 16));
            }
            *(float4*)(out + (size_t)itOut[it] * D + grp * 4) = o;
        }
    }
}

// ---------------------------------------------------------------------------
extern "C" void kernel_launch(void* const* d_in, const int* in_sizes, int n_in,
                              void* d_out, int out_size, void* d_ws, size_t ws_size,
                              hipStream_t stream) {
    const float* args   = (const float*)d_in[0];
    const int*   limits = (const int*)d_in[1];     // harness: integer -> const int*
    const float* W1     = (const float*)d_in[2];
    const float* b1     = (const float*)d_in[3];
    const float* W2     = (const float*)d_in[4];
    const float* b2     = (const float*)d_in[5];
    const float* lnw    = (const float*)d_in[6];
    const float* lnb    = (const float*)d_in[7];

    char* ws = (char*)d_ws;
    ushort* W1p       = (ushort*)(ws);            // 131072 B
    ushort* W2p       = (ushort*)(ws + 131072);   //  65536 B
    ushort* sortedIdx = (ushort*)(ws + 196608);   //   1024 B
    ushort* offRows   = (ushort*)(ws + 197632);   //   1024 B
    ushort* binStart  = (ushort*)(ws + 198656);   //   1040 B (520 u16)
    int*    nbins     = (int*)   (ws + 199744);   //      4 B  -> total < 200 KB

    pack_w_kernel<<<384, 256, 0, stream>>>(W1, W2, W1p, W2p);
    plan_kernel<<<1, 512, 0, stream>>>(limits, sortedIdx, offRows, binStart, nbins);
    tree_kernel<<<256, 512, 0, stream>>>(args, limits, W1p, W2p, b1, b2, lnw, lnb,
                                         sortedIdx, offRows, binStart, nbins, (float*)d_out);
}

// Round 7
// 102.430 us; speedup vs baseline: 4.1630x; 1.2102x over previous
//
#include <hip/hip_runtime.h>
#include <stdint.h>

#define D 128

typedef __bf16 bf16x8 __attribute__((ext_vector_type(8)));
typedef float f32x4  __attribute__((ext_vector_type(4)));

__device__ __forceinline__ float b2f(ushort u) {
    uint x = ((uint)u) << 16;
    return __builtin_bit_cast(float, x);
}
__device__ __forceinline__ ushort f2b(float f) {   // round-to-nearest-even
    uint u = __builtin_bit_cast(uint, f);
    u += 0x7FFFu + ((u >> 16) & 1u);
    return (ushort)(u >> 16);
}
// swizzle: XOR low-3 bits of the 16B slot with the 512B pair-row index
__device__ __forceinline__ int swz(int b) { return b ^ (((b >> 9) & 7) << 4); }

// ---------------------------------------------------------------------------
// Weight packing (fragment-major bf16): W1p[((kk*16+nt)*64+lane)*8+t] =
//   W1[kk*32 + 8*(lane>>4) + t][nt*16 + (lane&15)]
// ---------------------------------------------------------------------------
__global__ void pack_w_kernel(const float* __restrict__ W1, const float* __restrict__ W2,
                              ushort* __restrict__ W1p, ushort* __restrict__ W2p) {
    int g = blockIdx.x * blockDim.x + threadIdx.x;
    if (g < 65536) {
        int t = g & 7, l = (g >> 3) & 63, nt = (g >> 9) & 15, kk = g >> 13;
        int krow = kk * 32 + (l >> 4) * 8 + t;
        int col  = nt * 16 + (l & 15);
        W1p[g] = f2b(W1[krow * 256 + col]);
    } else {
        int g2 = g - 65536;
        if (g2 < 32768) {
            int t = g2 & 7, l = (g2 >> 3) & 63, nt = (g2 >> 9) & 7, kk = g2 >> 12;
            int krow = kk * 32 + (l >> 4) * 8 + t;
            int col  = nt * 16 + (l & 15);
            W2p[g2] = f2b(W2[krow * 128 + col]);
        }
    }
}

// ---------------------------------------------------------------------------
// Block-wide inclusive scan (512 threads), u64 payload.
// ---------------------------------------------------------------------------
__device__ __forceinline__ unsigned long long block_scan_u64(unsigned long long v,
                                                             unsigned long long* wsum) {
    int lane = threadIdx.x & 63, wv = threadIdx.x >> 6;
    unsigned long long x = v;
    #pragma unroll
    for (int o = 1; o < 64; o <<= 1) {
        unsigned long long y = __shfl_up(x, (unsigned)o, 64);
        if (lane >= o) x += y;
    }
    if (lane == 63) wsum[wv] = x;
    __syncthreads();
    if (threadIdx.x == 0) {
        unsigned long long acc = 0;
        for (int i = 0; i < 8; ++i) { unsigned long long t = wsum[i]; wsum[i] = acc; acc += t; }
    }
    __syncthreads();
    unsigned long long r = x + wsum[wv];
    __syncthreads();
    return r;
}

// ---------------------------------------------------------------------------
// Plan: pow2-pad items (min 4 rows), counting-sort descending, per-bin tables.
// ---------------------------------------------------------------------------
__global__ void __launch_bounds__(512) plan_kernel(
    const int* __restrict__ limits,
    ushort* __restrict__ sortedIdx, ushort* __restrict__ offRows,
    ushort* __restrict__ binStart, int* __restrict__ nbinsOut)
{
    __shared__ unsigned long long wsum[8];
    __shared__ int cnt[16], base[16];
    __shared__ ushort p2a[512], sIdx[512], binA[512];
    const int tid = threadIdx.x;

    int Lm = limits[tid + 1] - limits[tid];
    Lm = min(max(Lm, 1), 256);
    int p2 = (Lm <= 1) ? 4 : (1 << (32 - __clz(Lm - 1)));
    if (p2 < 4) p2 = 4;
    int cls = 31 - __clz(p2);             // 2..8
    p2a[tid] = (ushort)p2;
    if (tid < 16) cnt[tid] = 0;
    __syncthreads();
    atomicAdd(&cnt[cls], 1);
    __syncthreads();
    if (tid == 0) {
        int b = 0;
        for (int c = 8; c >= 2; --c) { base[c] = b; b += cnt[c]; }
    }
    __syncthreads();

    unsigned long long va = (cls <= 5) ? (1ull << ((cls - 2) * 16)) : 0ull;
    unsigned long long vb = (cls >= 6) ? (1ull << ((cls - 6) * 16)) : 0ull;
    unsigned long long ia = block_scan_u64(va, wsum);
    unsigned long long ib = block_scan_u64(vb, wsum);
    int rank = (cls <= 5) ? (int)((ia >> ((cls - 2) * 16)) & 0xFFFF) - 1
                          : (int)((ib >> ((cls - 6) * 16)) & 0xFFFF) - 1;
    int pos = base[cls] + rank;
    sIdx[pos] = (ushort)tid;
    __syncthreads();

    unsigned long long pv = (unsigned long long)p2a[sIdx[tid]];
    unsigned long long ic = block_scan_u64(pv, wsum);
    unsigned int cumB = (unsigned int)(ic - pv);
    int bin = (int)(cumB >> 8);
    binA[tid] = (ushort)bin;
    sortedIdx[tid] = sIdx[tid];
    offRows[tid]  = (ushort)(cumB & 255);
    __syncthreads();
    if (tid == 0) binStart[0] = 0;
    else if (binA[tid] != binA[tid - 1]) binStart[bin] = (ushort)tid;
    if (tid == 511) { nbinsOut[0] = bin + 1; binStart[bin + 1] = 512; }
}

// ---------------------------------------------------------------------------
// Level body, compile-time fragment count NMF: straight-line GEMM1 -> H wb ->
// GEMM2 -> LN/Y/leftover. Sentinel entries (prow=0, yd=0xFFFF) pad the tail;
// their fragments compute-and-discard (no guards in the unrolled loops).
// ---------------------------------------------------------------------------
template<int NMF>
__device__ __forceinline__ void level_body(
    char* __restrict__ Xw, const char* __restrict__ W2s,
    const unsigned* __restrict__ sk,
    const uint4 (&w1r)[8][2], const float (&bb1)[2][4],
    const float (&bb2)[8], const float (&lw)[8], const float (&lb)[8],
    const ushort* __restrict__ cpSk, const ushort* __restrict__ itOff,
    int G, int tid, int lane, int w)
{
    unsigned pa[NMF];
    #pragma unroll
    for (int mf = 0; mf < NMF; ++mf) pa[mf] = sk[mf * 16 + (lane & 15)];

    // GEMM1 swapped: acc1[n][mf] = H^T fragment
    f32x4 acc1[2][NMF];
    #pragma unroll
    for (int n = 0; n < 2; ++n)
        #pragma unroll
        for (int mf = 0; mf < NMF; ++mf) acc1[n][mf] = f32x4{0.f, 0.f, 0.f, 0.f};

    #pragma unroll
    for (int kk = 0; kk < 8; ++kk) {
        uint4 xv[NMF];
        #pragma unroll
        for (int mf = 0; mf < NMF; ++mf) {
            int prow = (int)(pa[mf] & 0xFFFFu);
            xv[mf] = *(const uint4*)(Xw + (prow * 512 + ((kk * 64 + (lane >> 4) * 16) ^ ((prow & 7) << 4))));
        }
        #pragma unroll
        for (int n = 0; n < 2; ++n) {
            bf16x8 af = __builtin_bit_cast(bf16x8, w1r[kk][n]);
            #pragma unroll
            for (int mf = 0; mf < NMF; ++mf)
                acc1[n][mf] = __builtin_amdgcn_mfma_f32_16x16x32_bf16(
                    af, __builtin_bit_cast(bf16x8, xv[mf]), acc1[n][mf], 0, 0, 0);
        }
    }
    __syncthreads();   // all X reads done

    // H write-back: lane holds 4 consecutive H cols of pair row -> b64 writes
    #pragma unroll
    for (int mf = 0; mf < NMF; ++mf) {
        if ((pa[mf] >> 16) != 0xFFFFu) {
            int prow = (int)(pa[mf] & 0xFFFFu);
            int rbase = prow * 512, sm = (prow & 7) << 4;
            #pragma unroll
            for (int n = 0; n < 2; ++n) {
                float h0 = fmaxf(acc1[n][mf][0] + bb1[n][0], 0.f);
                float h1 = fmaxf(acc1[n][mf][1] + bb1[n][1], 0.f);
                float h2 = fmaxf(acc1[n][mf][2] + bb1[n][2], 0.f);
                float h3 = fmaxf(acc1[n][mf][3] + bb1[n][3], 0.f);
                uint2 pk;
                pk.x = (uint)f2b(h0) | ((uint)f2b(h1) << 16);
                pk.y = (uint)f2b(h2) | ((uint)f2b(h3) << 16);
                *(uint2*)(Xw + (rbase + ((64 * w + 32 * n + 8 * (lane >> 4)) ^ sm))) = pk;
            }
        }
    }
    __syncthreads();   // H visible

    // GEMM2: M-split, wave w -> fragment w
    f32x4 acc2[8];
    #pragma unroll
    for (int nt = 0; nt < 8; ++nt) acc2[nt] = f32x4{0.f, 0.f, 0.f, 0.f};

    if (w < NMF) {
        int prow = (int)(sk[w * 16 + (lane & 15)] & 0xFFFFu);
        int sm = (prow & 7) << 4, rbase = prow * 512;
        #pragma unroll
        for (int kk = 0; kk < 8; ++kk) {
            uint4 av = *(const uint4*)(Xw + (rbase + ((kk * 64 + (lane >> 4) * 16) ^ sm)));
            bf16x8 af = __builtin_bit_cast(bf16x8, av);
            #pragma unroll
            for (int nt = 0; nt < 8; ++nt) {
                uint4 bv = *(const uint4*)(W2s + (((kk * 8 + nt) * 64 + lane) << 4));
                acc2[nt] = __builtin_amdgcn_mfma_f32_16x16x32_bf16(
                    af, __builtin_bit_cast(bf16x8, bv), acc2[nt], 0, 0, 0);
            }
        }
    }
    __syncthreads();   // all H reads done

    // LayerNorm + compacted Y write
    if (w < NMF) {
        float yv[8][4];
        float s1[4] = {0.f,0.f,0.f,0.f}, s2[4] = {0.f,0.f,0.f,0.f};
        #pragma unroll
        for (int nt = 0; nt < 8; ++nt)
            #pragma unroll
            for (int i = 0; i < 4; ++i) {
                float v = acc2[nt][i] + bb2[nt];
                yv[nt][i] = v; s1[i] += v; s2[i] += v * v;
            }
        #pragma unroll
        for (int o = 1; o < 16; o <<= 1)
            #pragma unroll
            for (int i = 0; i < 4; ++i) {
                s1[i] += __shfl_xor(s1[i], o, 64);
                s2[i] += __shfl_xor(s2[i], o, 64);
            }
        float mu[4], rs[4];
        #pragma unroll
        for (int i = 0; i < 4; ++i) {
            mu[i] = s1[i] * (1.f / 128.f);
            float var = s2[i] * (1.f / 128.f) - mu[i] * mu[i];
            rs[i] = rsqrtf(var + 1e-5f);
        }
        #pragma unroll
        for (int i = 0; i < 4; ++i) {
            unsigned se = sk[w * 16 + (lane >> 4) * 4 + i];
            int yd = (int)(se >> 16);
            if (yd != 0xFFFF) {
                #pragma unroll
                for (int nt = 0; nt < 8; ++nt) {
                    int c = nt * 16 + (lane & 15);
                    float v = (yv[nt][i] - mu[i]) * rs[i] * lw[nt] + lb[nt];
                    *(ushort*)(Xw + swz(yd * 256 + c * 2)) = f2b(v);
                }
            }
        }
    }
    // leftover rows: copy row (l-1) -> row itOff per odd item
    #pragma unroll
    for (int q = 0; q < 2; ++q) {
        int it = q * 32 + (tid >> 4);
        if (it < G) {
            int srow = (int)cpSk[it];
            if (srow != 0xFFFF) {
                int ch = tid & 15;
                uint4 v = *(const uint4*)(Xw + swz(srow * 256 + ch * 16));
                *(uint4*)(Xw + swz((int)itOff[it] * 256 + ch * 16)) = v;
            }
        }
    }
}

// ---------------------------------------------------------------------------
// Fused tree kernel v5: round-4/5 planning (binary searches, known-good)
// + NMF-templated straight-line level bodies. Persistent blocks (grid 256).
// W1 in regs, W2 in LDS.
// ---------------------------------------------------------------------------
__global__ void __launch_bounds__(512, 2) tree_kernel(
    const float* __restrict__ args, const int* __restrict__ limits,
    const ushort* __restrict__ W1p, const ushort* __restrict__ W2p,
    const float* __restrict__ b1, const float* __restrict__ b2,
    const float* __restrict__ lnw, const float* __restrict__ lnb,
    const ushort* __restrict__ sortedIdx, const ushort* __restrict__ offRows,
    const ushort* __restrict__ binStart, const int* __restrict__ nbinsP,
    float* __restrict__ out)
{
    __shared__ __align__(16) char Xw[65536];
    __shared__ __align__(16) char W2s[65536];
    __shared__ unsigned int schedAll[1024];     // 8 levels x 128 entries
    __shared__ ushort cpSAll[8][64];
    __shared__ ushort itOff[64], itL[64], itOut[64], startP[64], ybS[64];
    __shared__ int itRow[64];
    __shared__ int nPAll[8];
    __shared__ int gmisc[2];   // 0:G  1:nlev

    const int tid = threadIdx.x, lane = tid & 63, w = tid >> 6;
    const int nbins = *nbinsP;

    // ---- one-time per block: W1 slice -> regs (wave w owns H cols 32w..32w+31)
    uint4 w1r[8][2];
    #pragma unroll
    for (int kk = 0; kk < 8; ++kk)
        #pragma unroll
        for (int n = 0; n < 2; ++n)
            w1r[kk][n] = *(const uint4*)(W1p + (size_t)(((kk * 16 + (w * 2 + n)) * 64 + lane) << 3));

    // epilogue constants. GEMM1 (swapped) lane holds H cols 32w+16n+4*(lane>>4)+i
    float bb1[2][4];
    #pragma unroll
    for (int n = 0; n < 2; ++n)
        #pragma unroll
        for (int i = 0; i < 4; ++i)
            bb1[n][i] = b1[32 * w + 16 * n + 4 * (lane >> 4) + i];
    float bb2[8], lw[8], lb[8];
    #pragma unroll
    for (int nt = 0; nt < 8; ++nt) {
        int c = nt * 16 + (lane & 15);
        bb2[nt] = b2[c]; lw[nt] = lnw[c]; lb[nt] = lnb[c];
    }

    // ---- one-time per block: W2 packed -> LDS (64KB)
    #pragma unroll
    for (int q = 0; q < 8; ++q) {
        int t = tid + q * 512;
        *(uint4*)(W2s + t * 16) = *(const uint4*)((const char*)W2p + t * 16);
    }

    for (int bin = blockIdx.x; bin < nbins; bin += gridDim.x) {
        __syncthreads();   // previous bin's LDS readers done
        if (tid == 0) gmisc[0] = (int)binStart[bin + 1] - (int)binStart[bin];
        __syncthreads();
        const int G = gmisc[0];

        if (tid < G) {
            int pos = (int)binStart[bin] + tid;
            int it = sortedIdx[pos];
            itOff[tid] = offRows[pos];
            int a0 = limits[it];
            int Lm = min(max(limits[it + 1] - a0, 1), 256);
            itL[tid] = (ushort)Lm;
            itRow[tid] = a0; itOut[tid] = (ushort)it;
        }
        if (tid < 64) {
            int lev = 0;
            if (tid < G) { int Lm = (int)itL[tid]; lev = (Lm > 1) ? (32 - __clz(Lm - 1)) : 0; }
            #pragma unroll
            for (int o = 32; o; o >>= 1) lev = max(lev, __shfl_xor(lev, o, 64));
            if (tid == 0) gmisc[1] = lev;
        }
        __syncthreads();
        const int nlev = gmisc[1];

        // ---- phase A: wave0 builds all-level schedules (binary search, known-good);
        //      waves 1..7 stage leaves (binary search per job, known-good)
        if (w == 0) {
            int l   = (lane < G) ? (int)itL[lane] : 0;
            int off = (lane < G) ? (int)itOff[lane] : 0;
            for (int k = 0; k < nlev; ++k) {
                int p = l >> 1;
                int x = p;
                #pragma unroll
                for (int o = 1; o < 64; o <<= 1) { int y = __shfl_up(x, (unsigned)o, 64); if (lane >= o) x += y; }
                int excl = x - p;
                int nPk = __shfl(x, 63, 64);
                if (lane == 0) nPAll[k] = nPk;
                startP[lane] = (ushort)excl;
                ybS[lane]    = (ushort)(off + (l & 1));
                cpSAll[k][lane] = (l > 1 && (l & 1)) ? (ushort)(off + l - 1) : (ushort)0xFFFF;
                #pragma unroll
                for (int rep = 0; rep < 2; ++rep) {
                    int e = lane + rep * 64;
                    unsigned entry = 0xFFFF0000u;
                    if (e < nPk) {
                        int lo = 0, hi = G;
                        while (hi - lo > 1) { int mid = (lo + hi) >> 1; if ((int)startP[mid] <= e) lo = mid; else hi = mid; }
                        int j = e - (int)startP[lo];
                        entry = (unsigned)(((int)itOff[lo] >> 1) + j) | ((unsigned)((int)ybS[lo] + j) << 16);
                    }
                    schedAll[k * 128 + e] = entry;
                }
                l = p + (l & 1);
            }
        } else {
            // ---- leaf staging by waves 1..7 (f32 -> bf16, swizzled)
            for (int job = tid - 64; job < 4096; job += 448) {
                int r = job >> 4, ch = job & 15;
                int lo = 0, hi = G;
                while (hi - lo > 1) { int mid = (lo + hi) >> 1; if ((int)itOff[mid] <= r) lo = mid; else hi = mid; }
                int rel = r - (int)itOff[lo];
                if (rel >= 0 && rel < (int)itL[lo]) {
                    int src = itRow[lo] + rel;
                    const float4 f0 = *(const float4*)(args + (size_t)src * D + ch * 8);
                    const float4 f1 = *(const float4*)(args + (size_t)src * D + ch * 8 + 4);
                    uint4 pk;
                    pk.x = (uint)f2b(f0.x) | ((uint)f2b(f0.y) << 16);
                    pk.y = (uint)f2b(f0.z) | ((uint)f2b(f0.w) << 16);
                    pk.z = (uint)f2b(f1.x) | ((uint)f2b(f1.y) << 16);
                    pk.w = (uint)f2b(f1.z) | ((uint)f2b(f1.w) << 16);
                    *(uint4*)(Xw + swz(r * 256 + ch * 16)) = pk;
                }
            }
        }
        __syncthreads();

        // ---- level loop (NMF-templated straight-line bodies)
        for (int k = 0; k < nlev; ++k) {
            const int nP = nPAll[k];
            if (nP == 0) break;
            const int nMf = (nP + 15) >> 4;
            const unsigned* sk = schedAll + k * 128;
            if (nMf > 4)
                level_body<8>(Xw, W2s, sk, w1r, bb1, bb2, lw, lb, cpSAll[k], itOff, G, tid, lane, w);
            else if (nMf > 2)
                level_body<4>(Xw, W2s, sk, w1r, bb1, bb2, lw, lb, cpSAll[k], itOff, G, tid, lane, w);
            else if (nMf == 2)
                level_body<2>(Xw, W2s, sk, w1r, bb1, bb2, lw, lb, cpSAll[k], itOff, G, tid, lane, w);
            else
                level_body<1>(Xw, W2s, sk, w1r, bb1, bb2, lw, lb, cpSAll[k], itOff, G, tid, lane, w);
            __syncthreads();
        }

        // ---- output: root = live row itOff of each item; L==1 exact f32
        for (int j = tid; j < G * 32; j += 512) {
            int it = j >> 5, grp = j & 31;
            float4 o;
            if ((int)itL[it] == 1) {
                o = *(const float4*)(args + (size_t)itRow[it] * D + grp * 4);
            } else {
                uint2 v = *(const uint2*)(Xw + swz((int)itOff[it] * 256 + grp * 8));
                o.x = b2f((ushort)(v.x & 0xFFFFu));
                o.y = b2f((ushort)(v.x >> 16));
                o.z = b2f((ushort)(v.y & 0xFFFFu));
                o.w = b2f((ushort)(v.y >> 16));
            }
            *(float4*)(out + (size_t)itOut[it] * D + grp * 4) = o;
        }
    }
}

// ---------------------------------------------------------------------------
extern "C" void kernel_launch(void* const* d_in, const int* in_sizes, int n_in,
                              void* d_out, int out_size, void* d_ws, size_t ws_size,
                              hipStream_t stream) {
    const float* args   = (const float*)d_in[0];
    const int*   limits = (const int*)d_in[1];     // harness: integer -> const int*
    const float* W1     = (const float*)d_in[2];
    const float* b1     = (const float*)d_in[3];
    const float* W2     = (const float*)d_in[4];
    const float* b2     = (const float*)d_in[5];
    const float* lnw    = (const float*)d_in[6];
    const float* lnb    = (const float*)d_in[7];

    char* ws = (char*)d_ws;
    ushort* W1p       = (ushort*)(ws);            // 131072 B
    ushort* W2p       = (ushort*)(ws + 131072);   //  65536 B
    ushort* sortedIdx = (ushort*)(ws + 196608);   //   1024 B
    ushort* offRows   = (ushort*)(ws + 197632);   //   1024 B
    ushort* binStart  = (ushort*)(ws + 198656);   //   1040 B
    int*    nbins     = (int*)   (ws + 199744);   //      4 B

    pack_w_kernel<<<384, 256, 0, stream>>>(W1, W2, W1p, W2p);
    plan_kernel<<<1, 512, 0, stream>>>(limits, sortedIdx, offRows, binStart, nbins);
    tree_kernel<<<256, 512, 0, stream>>>(args, limits, W1p, W2p, b1, b2, lnw, lnb,
                                         sortedIdx, offRows, binStart, nbins, (float*)d_out);
}